// Round 9
// baseline (435.092 us; speedup 1.0000x reference)
//
#include <hip/hip_runtime.h>
#include <stdint.h>

// ---------------------------------------------------------------------------
// SAGEConv variant (acmgraphsage), f32, N=65536, E=1048576, D=64.
// Round 9: R6 pipeline restored (NPB=64, 512-thr k_gf, wave-uniform octants).
// k_gf v3: software-pipelined fusion of gather (phase 2) and GEMV (phase 3)
// per dd-iteration — gather loads in flight under GEMV FMAs. feat tile in
// LDS; sorted/red aliased (union) to keep 4 blocks/CU at ~39.9 KB LDS.
// Pipeline: tf_hist -> scan_part/top/down -> bin_scatter -> gf
// ---------------------------------------------------------------------------

#define NBLK 256     // edge-blocks for binning
#define NBUC 1024    // coarse buckets = dst >> 6
#define NPB  64      // nodes per bucket
#define GCAP 2048    // max edges per bucket (avg 1024, ~32 sigma headroom)
#define MTOT (NBUC * NBLK)      // 262144
#define NPART 256               // MTOT / 1024

__device__ __forceinline__ void load_feat(const float* __restrict__ feat, size_t base,
                                          float* __restrict__ f) {
    const float4* fp = (const float4*)(feat + base);
#pragma unroll
    for (int i = 0; i < 16; ++i) {
        float4 v = fp[i];
        f[4 * i + 0] = v.x; f[4 * i + 1] = v.y;
        f[4 * i + 2] = v.z; f[4 * i + 3] = v.w;
    }
}

__device__ __forceinline__ uint32_t bf16_rne(float x) {
    uint32_t u = __float_as_uint(x);
    return (u + 0x7fffu + ((u >> 16) & 1u)) >> 16;
}

// ---- fused: blocks [0,nTf) transform nodes; blocks [nTf, nTf+NBLK) histogram.
__global__ void __launch_bounds__(512)
k_tf_hist(const float* __restrict__ feat, const float* __restrict__ norm,
          const float* __restrict__ Wn, const float* __restrict__ bn,
          const float* __restrict__ Wnh, const float* __restrict__ bnh,
          uint32_t* __restrict__ h_pk,
          const int* __restrict__ dst, int* __restrict__ blk_cnt,
          int N, int E, int nTf)
{
    __shared__ int cnt[NBUC];
    int t = threadIdx.x;

    if ((int)blockIdx.x >= nTf) {
        int hb = blockIdx.x - nTf;
        for (int i = t; i < NBUC; i += 512) cnt[i] = 0;
        __syncthreads();
        int epb = (E + NBLK - 1) / NBLK;
        int eb = hb * epb;
        for (int i0 = t * 8; i0 < epb; i0 += 512 * 8) {
            int e = eb + i0;
            if (e + 8 <= E) {
                int4 d0 = *(const int4*)(dst + e);
                int4 d1 = *(const int4*)(dst + e + 4);
                atomicAdd(&cnt[((unsigned)d0.x) >> 6], 1);
                atomicAdd(&cnt[((unsigned)d0.y) >> 6], 1);
                atomicAdd(&cnt[((unsigned)d0.z) >> 6], 1);
                atomicAdd(&cnt[((unsigned)d0.w) >> 6], 1);
                atomicAdd(&cnt[((unsigned)d1.x) >> 6], 1);
                atomicAdd(&cnt[((unsigned)d1.y) >> 6], 1);
                atomicAdd(&cnt[((unsigned)d1.z) >> 6], 1);
                atomicAdd(&cnt[((unsigned)d1.w) >> 6], 1);
            } else {
                for (int j = 0; j < 8; ++j) {
                    int ee = e + j;
                    if (ee < E) atomicAdd(&cnt[((unsigned)dst[ee]) >> 6], 1);
                }
            }
        }
        __syncthreads();
        for (int i = t; i < NBUC; i += 512)
            blk_cnt[i * NBLK + hb] = cnt[i];
        return;
    }

    int nsub = t & 63;
    int q = __builtin_amdgcn_readfirstlane(t >> 6);
    int n = blockIdx.x * 64 + nsub;
    if (n >= N) return;

    size_t base = (size_t)n << 6;
    float f[64];
    load_feat(feat, base, f);
    float nr = norm[n];

    uint32_t pk[8];
#pragma unroll
    for (int jj = 0; jj < 8; ++jj) {
        int j = q * 8 + jj;
        const float4* rL = (const float4*)(Wn  + ((size_t)j << 6));
        const float4* rH = (const float4*)(Wnh + ((size_t)j << 6));
        float sL = 0.f, sH = 0.f;
#pragma unroll
        for (int k4 = 0; k4 < 16; ++k4) {
            float4 wL = rL[k4];
            float4 wH = rH[k4];
            sL = fmaf(f[4*k4+0], wL.x, sL); sL = fmaf(f[4*k4+1], wL.y, sL);
            sL = fmaf(f[4*k4+2], wL.z, sL); sL = fmaf(f[4*k4+3], wL.w, sL);
            sH = fmaf(f[4*k4+0], wH.x, sH); sH = fmaf(f[4*k4+1], wH.y, sH);
            sH = fmaf(f[4*k4+2], wH.z, sH); sH = fmaf(f[4*k4+3], wH.w, sH);
        }
        float oL = fmaxf(sL + bn[j],  0.f) * nr;
        float oH = fmaxf(sH + bnh[j], 0.f) * nr;
        pk[jj] = bf16_rne(oL) | (bf16_rne(oH) << 16);
    }
    uint4* pp = (uint4*)(h_pk + base + q * 8);
    pp[0] = make_uint4(pk[0], pk[1], pk[2], pk[3]);
    pp[1] = make_uint4(pk[4], pk[5], pk[6], pk[7]);
}

// ---- hierarchical exclusive scan of blk_cnt[0..MTOT) -> blk_off[0..MTOT].
__global__ void __launch_bounds__(256)
k_scan_part(const int* __restrict__ cnt_in, int* __restrict__ part)
{
    __shared__ int red[256];
    int t = threadIdx.x;
    const int4* A4 = (const int4*)cnt_in;
    int4 v = A4[blockIdx.x * 256 + t];
    int s = v.x + v.y + v.z + v.w;
    red[t] = s;
    __syncthreads();
    for (int off = 128; off > 0; off >>= 1) {
        if (t < off) red[t] += red[t + off];
        __syncthreads();
    }
    if (t == 0) part[blockIdx.x] = red[0];
}

__global__ void __launch_bounds__(256)
k_scan_top(const int* __restrict__ part, int* __restrict__ top)
{
    __shared__ int s[NPART];
    int t = threadIdx.x;
    int mine = part[t];
    s[t] = mine;
    __syncthreads();
    for (int off = 1; off < NPART; off <<= 1) {
        int v = s[t];
        int a = (t >= off) ? s[t - off] : 0;
        __syncthreads();
        s[t] = v + a;
        __syncthreads();
    }
    top[t] = s[t] - mine;           // exclusive
}

__global__ void __launch_bounds__(256)
k_scan_down(const int* __restrict__ cnt_in, const int* __restrict__ top,
            int* __restrict__ off_out)
{
    __shared__ int s[256];
    int t = threadIdx.x;
    const int4* A4 = (const int4*)cnt_in;
    int4 v = A4[blockIdx.x * 256 + t];
    int sum = v.x + v.y + v.z + v.w;
    s[t] = sum;
    __syncthreads();
    for (int off = 1; off < 256; off <<= 1) {
        int vv = s[t];
        int a = (t >= off) ? s[t - off] : 0;
        __syncthreads();
        s[t] = vv + a;
        __syncthreads();
    }
    int run = top[blockIdx.x] + s[t] - sum;
    int4 o;
    o.x = run; run += v.x;
    o.y = run; run += v.y;
    o.z = run; run += v.z;
    o.w = run; run += v.w;
    ((int4*)off_out)[blockIdx.x * 256 + t] = o;
    if (blockIdx.x == (NPART - 1) && t == 255) off_out[MTOT] = run;
}

// ---- scatter edges into coarse buckets; rank via LDS atomics, contiguous runs.
__global__ void __launch_bounds__(512)
k_bin_scatter(const int* __restrict__ src, const int* __restrict__ dst,
              const int* __restrict__ blk_off, uint32_t* __restrict__ ebuf, int E)
{
    __shared__ int base_[NBUC];
    __shared__ int cnt[NBUC];
    int t = threadIdx.x;
    for (int i = t; i < NBUC; i += 512) {
        base_[i] = blk_off[i * NBLK + blockIdx.x];
        cnt[i] = 0;
    }
    __syncthreads();
    int epb = (E + NBLK - 1) / NBLK;
    int eb = blockIdx.x * epb;
    for (int i0 = t * 8; i0 < epb; i0 += 512 * 8) {
        int e = eb + i0;
        if (e + 8 <= E) {
            int4 d0 = *(const int4*)(dst + e);
            int4 d1 = *(const int4*)(dst + e + 4);
            int4 s0 = *(const int4*)(src + e);
            int4 s1 = *(const int4*)(src + e + 4);
            int da[8] = { d0.x, d0.y, d0.z, d0.w, d1.x, d1.y, d1.z, d1.w };
            int sa[8] = { s0.x, s0.y, s0.z, s0.w, s1.x, s1.y, s1.z, s1.w };
#pragma unroll
            for (int j = 0; j < 8; ++j) {
                int b = ((unsigned)da[j]) >> 6;
                int r = atomicAdd(&cnt[b], 1);
                ebuf[base_[b] + r] = ((uint32_t)(da[j] & 63) << 16) | (uint32_t)sa[j];
            }
        } else {
            for (int j = 0; j < 8; ++j) {
                int ee = e + j;
                if (ee < E) {
                    int d = dst[ee];
                    int b = ((unsigned)d) >> 6;
                    int r = atomicAdd(&cnt[b], 1);
                    ebuf[base_[b] + r] = ((uint32_t)(d & 63) << 16) | (uint32_t)src[ee];
                }
            }
        }
    }
}

// ---- fused gather + att + out, software-pipelined.
// Block = bucket = 64 dst nodes, 512 threads, 8 waves. Wave w, lane l:
//   per dd: gathers channel l of node w*8+dd  AND  GEMV row w*8+dd of node l.
__global__ void __launch_bounds__(512)
k_gf(const uint32_t* __restrict__ h_pk, const int* __restrict__ blk_off,
     const uint32_t* __restrict__ ebuf,
     const float* __restrict__ feat,
     const float* __restrict__ Ws, const float* __restrict__ bs,
     const float* __restrict__ Wsh, const float* __restrict__ bsh,
     const float* __restrict__ Wid, const float* __restrict__ bid,
     const float* __restrict__ wl, const float* __restrict__ wh,
     const float* __restrict__ wm, const float* __restrict__ Watt,
     float* __restrict__ out, int N)
{
    __shared__ union {
        unsigned short sorted[GCAP + 16];   // phase 1-2
        float red[3][8][64];                // combine reduce (after barrier)
    } u;
    __shared__ int s_cnt[NPB];
    __shared__ int s_off[NPB];
    __shared__ uint32_t s_m[NPB][65];       // bf16x2-packed means, padded
    __shared__ float sf[64][65];            // feat tile, padded (conflict-free)

    int b = blockIdx.x;
    int t = threadIdx.x;

    // stage feat tile: thread t -> node t>>3, channels (t&7)*8 .. +7
    {
        int nn = t >> 3;
        int c0 = (t & 7) * 8;
        const float* fp = feat + (((size_t)(b * 64 + nn)) << 6) + c0;
#pragma unroll
        for (int k = 0; k < 8; ++k) sf[nn][c0 + k] = fp[k];
    }

    int es = blk_off[b * NBLK];
    int ee = blk_off[(b + 1) * NBLK];
    int ne = ee - es;
    if (ne > GCAP) ne = GCAP;                 // never in practice
    if (t < NPB) s_cnt[t] = 0;
    __syncthreads();

    // phase 1: read bucket edges, rank per node, counting-sort into LDS
    int ed[4], er[4], esrc[4];
#pragma unroll
    for (int i = 0; i < 4; ++i) {
        int idx = i * 512 + t;
        ed[i] = -1;
        if (idx < ne) {
            uint32_t v = ebuf[es + idx];
            ed[i] = (int)(v >> 16);
            esrc[i] = (int)(v & 0xffffu);
            er[i] = atomicAdd(&s_cnt[ed[i]], 1);
        }
    }
    __syncthreads();
    if (t < 64) {                              // wave-0 exclusive scan of 64 counts
        int c = s_cnt[t];
        int sc = c;
        for (int o = 1; o < 64; o <<= 1) {
            int uu = __shfl_up(sc, o, 64);
            if (t >= o) sc += uu;
        }
        s_off[t] = sc - c;
    }
    __syncthreads();
#pragma unroll
    for (int i = 0; i < 4; ++i)
        if (ed[i] >= 0) u.sorted[s_off[ed[i]] + er[i]] = (unsigned short)esrc[i];
    __syncthreads();

    // fused phase 2+3: per dd, issue gather loads -> GEMV row -> consume.
    int w = __builtin_amdgcn_readfirstlane(t >> 6);   // wave id == octant q
    int lane = t & 63;                                // gather channel == GEMV node
    float aL[8], aH[8], aI[8];

#pragma unroll
    for (int dd = 0; dd < 8; ++dd) {
        int d = w * 8 + dd;                   // gather node (wave-uniform)
        int cd = s_cnt[d];
        int od = s_off[d];

        // --- issue first up-to-8 gather loads (wave-uniform count) ---
        uint32_t v[8];
        int n0 = cd < 8 ? cd : 8;
#pragma unroll
        for (int k = 0; k < 8; ++k) {
            int idx = (k < n0) ? (od + k) : od;
            int s0 = u.sorted[idx];
            v[k] = (k < n0) ? h_pk[((size_t)s0 << 6) + lane] : 0u;
        }

        // --- GEMV row j = w*8+dd of node `lane` (hides the loads) ---
        {
            int j = w * 8 + dd;               // wave-uniform row
            const float4* rL = (const float4*)(Ws  + ((size_t)j << 6));
            const float4* rH = (const float4*)(Wsh + ((size_t)j << 6));
            const float4* rI = (const float4*)(Wid + ((size_t)j << 6));
            float sL = 0.f, sH = 0.f, sI = 0.f;
#pragma unroll
            for (int k4 = 0; k4 < 16; ++k4) {
                float4 wL = rL[k4];
                float4 wH = rH[k4];
                float4 wI = rI[k4];
                float f0 = sf[lane][4*k4+0];
                float f1 = sf[lane][4*k4+1];
                float f2 = sf[lane][4*k4+2];
                float f3 = sf[lane][4*k4+3];
                sL = fmaf(f0, wL.x, sL); sL = fmaf(f1, wL.y, sL);
                sL = fmaf(f2, wL.z, sL); sL = fmaf(f3, wL.w, sL);
                sH = fmaf(f0, wH.x, sH); sH = fmaf(f1, wH.y, sH);
                sH = fmaf(f2, wH.z, sH); sH = fmaf(f3, wH.w, sH);
                sI = fmaf(f0, wI.x, sI); sI = fmaf(f1, wI.y, sI);
                sI = fmaf(f2, wI.z, sI); sI = fmaf(f3, wI.w, sI);
            }
            aL[dd] = fmaxf(sL + bs[j],  0.f);
            aH[dd] = fmaxf(sH + bsh[j], 0.f);
            aI[dd] = fmaxf(sI + bid[j], 0.f);
        }

        // --- consume prologue + remainder gather ---
        float accL = 0.f, accH = 0.f;
#pragma unroll
        for (int k = 0; k < 8; ++k) {
            if (k < n0) {
                accL += __uint_as_float(v[k] << 16);
                accH += __uint_as_float(v[k] & 0xffff0000u);
            }
        }
        int i = 8;
        for (; i + 8 <= cd; i += 8) {
            int s0 = u.sorted[od + i + 0];
            int s1 = u.sorted[od + i + 1];
            int s2 = u.sorted[od + i + 2];
            int s3 = u.sorted[od + i + 3];
            int s4 = u.sorted[od + i + 4];
            int s5 = u.sorted[od + i + 5];
            int s6 = u.sorted[od + i + 6];
            int s7 = u.sorted[od + i + 7];
            uint32_t v0 = h_pk[((size_t)s0 << 6) + lane];
            uint32_t v1 = h_pk[((size_t)s1 << 6) + lane];
            uint32_t v2 = h_pk[((size_t)s2 << 6) + lane];
            uint32_t v3 = h_pk[((size_t)s3 << 6) + lane];
            uint32_t v4 = h_pk[((size_t)s4 << 6) + lane];
            uint32_t v5 = h_pk[((size_t)s5 << 6) + lane];
            uint32_t v6 = h_pk[((size_t)s6 << 6) + lane];
            uint32_t v7 = h_pk[((size_t)s7 << 6) + lane];
            accL += (__uint_as_float(v0 << 16) + __uint_as_float(v1 << 16))
                  + (__uint_as_float(v2 << 16) + __uint_as_float(v3 << 16))
                  + (__uint_as_float(v4 << 16) + __uint_as_float(v5 << 16))
                  + (__uint_as_float(v6 << 16) + __uint_as_float(v7 << 16));
            accH += (__uint_as_float(v0 & 0xffff0000u) + __uint_as_float(v1 & 0xffff0000u))
                  + (__uint_as_float(v2 & 0xffff0000u) + __uint_as_float(v3 & 0xffff0000u))
                  + (__uint_as_float(v4 & 0xffff0000u) + __uint_as_float(v5 & 0xffff0000u))
                  + (__uint_as_float(v6 & 0xffff0000u) + __uint_as_float(v7 & 0xffff0000u));
        }
        for (; i < cd; ++i) {
            int s0 = u.sorted[od + i];
            uint32_t v0 = h_pk[((size_t)s0 << 6) + lane];
            accL += __uint_as_float(v0 << 16);
            accH += __uint_as_float(v0 & 0xffff0000u);
        }
        float inv = 1.f / fmaxf((float)cd, 1.f);
        s_m[d][lane] = bf16_rne(accL * inv) | (bf16_rne(accH * inv) << 16);
    }
    __syncthreads();

    // combine: add means, attention dots, softmax, output.
    int nsub = lane;
    int q = w;
    int n = b * 64 + nsub;
    size_t base = (size_t)n << 6;

    float dLp = 0.f, dHp = 0.f, dIp = 0.f;
#pragma unroll
    for (int jj = 0; jj < 8; ++jj) {
        int j = q * 8 + jj;
        uint32_t mv = s_m[nsub][j];
        float lowj  = aL[jj] + __uint_as_float(mv << 16);
        float highj = aH[jj] - __uint_as_float(mv & 0xffff0000u);
        aL[jj] = lowj;
        aH[jj] = highj;
        dLp = fmaf(lowj,   wl[j], dLp);
        dHp = fmaf(highj,  wh[j], dHp);
        dIp = fmaf(aI[jj], wm[j], dIp);
    }

    u.red[0][q][nsub] = dLp;
    u.red[1][q][nsub] = dHp;
    u.red[2][q][nsub] = dIp;
    __syncthreads();
    float dL = 0.f, dH = 0.f, dI = 0.f;
#pragma unroll
    for (int p = 0; p < 8; ++p) {
        dL += u.red[0][p][nsub];
        dH += u.red[1][p][nsub];
        dI += u.red[2][p][nsub];
    }

    float s0 = 1.f / (1.f + expf(-dL));
    float s1 = 1.f / (1.f + expf(-dH));
    float s2 = 1.f / (1.f + expf(-dI));
    const float third = (1.f / 3.f);
    float z0 = (Watt[0] * s0 + Watt[1] * s1 + Watt[2] * s2) * third;
    float z1 = (Watt[3] * s0 + Watt[4] * s1 + Watt[5] * s2) * third;
    float z2 = (Watt[6] * s0 + Watt[7] * s1 + Watt[8] * s2) * third;
    float m = fmaxf(z0, fmaxf(z1, z2));
    float e0 = expf(z0 - m), e1 = expf(z1 - m), e2 = expf(z2 - m);
    float r = 3.f / (e0 + e1 + e2);
    float a0 = e0 * r, a1 = e1 * r, a2 = e2 * r;

    float o[8];
#pragma unroll
    for (int jj = 0; jj < 8; ++jj)
        o[jj] = a0 * aL[jj] + a1 * aH[jj] + a2 * aI[jj];
    float* po = out + base + q * 8;
    *(float4*)(po + 0) = make_float4(o[0], o[1], o[2], o[3]);
    *(float4*)(po + 4) = make_float4(o[4], o[5], o[6], o[7]);
}

extern "C" void kernel_launch(void* const* d_in, const int* in_sizes, int n_in,
                              void* d_out, int out_size, void* d_ws, size_t ws_size,
                              hipStream_t stream) {
    const float* feat         = (const float*)d_in[0];
    const float* norm         = (const float*)d_in[1];
    const int*   src          = (const int*)d_in[2];
    const int*   dst          = (const int*)d_in[3];
    const float* W_self       = (const float*)d_in[4];
    const float* b_self       = (const float*)d_in[5];
    const float* W_self_high  = (const float*)d_in[6];
    const float* b_self_high  = (const float*)d_in[7];
    const float* W_neigh      = (const float*)d_in[8];
    const float* b_neigh      = (const float*)d_in[9];
    const float* W_neigh_high = (const float*)d_in[10];
    const float* b_neigh_high = (const float*)d_in[11];
    const float* W_id         = (const float*)d_in[12];
    const float* b_id         = (const float*)d_in[13];
    const float* w_att_low    = (const float*)d_in[14];
    const float* w_att_high   = (const float*)d_in[15];
    const float* w_att_mlp    = (const float*)d_in[16];
    const float* W_att        = (const float*)d_in[17];

    int N = in_sizes[0] / 64;
    int E = in_sizes[2];
    float* out = (float*)d_out;

    size_t N64 = (size_t)N * 64;

    uint32_t* h_pk    = (uint32_t*)d_ws;                  // N*64 u32 (16 MB)
    int*      blk_cnt = (int*)(h_pk + N64);               // MTOT int
    int*      blk_off = blk_cnt + MTOT;                   // MTOT+1 int
    int*      part    = blk_off + MTOT + 16;              // NPART int
    int*      top     = part + NPART + 16;                // NPART int
    uint32_t* ebuf    = (uint32_t*)(top + NPART + 16);    // E u32 (4 MB)

    int nTf = (N + 63) / 64;

    k_tf_hist<<<dim3(nTf + NBLK), dim3(512), 0, stream>>>(
        feat, norm, W_neigh, b_neigh, W_neigh_high, b_neigh_high, h_pk,
        dst, blk_cnt, N, E, nTf);
    k_scan_part<<<dim3(NPART), dim3(256), 0, stream>>>(blk_cnt, part);
    k_scan_top<<<dim3(1), dim3(NPART), 0, stream>>>(part, top);
    k_scan_down<<<dim3(NPART), dim3(256), 0, stream>>>(blk_cnt, top, blk_off);
    k_bin_scatter<<<dim3(NBLK), dim3(512), 0, stream>>>(src, dst, blk_off, ebuf, E);
    k_gf<<<dim3(NBUC), dim3(512), 0, stream>>>(h_pk, blk_off, ebuf, feat,
                                               W_self, b_self,
                                               W_self_high, b_self_high,
                                               W_id, b_id, w_att_low, w_att_high,
                                               w_att_mlp, W_att, out, N);
}

// Round 10
// 138.714 us; speedup vs baseline: 3.1366x; 3.1366x over previous
//
#include <hip/hip_runtime.h>
#include <stdint.h>

// ---------------------------------------------------------------------------
// SAGEConv variant (acmgraphsage), f32, N=65536, E=1048576, D=64.
// Round 10: restore the verified R6 configuration (139.3 us). R7/R8/R9
// established that the gather fill (~114 MB compulsory cross-XCD traffic at
// the per-XCD L2-miss-path rate) is the structural floor; all overlap /
// request-shape / occupancy levers were null or regressions.
// Pipeline: tf_hist -> scan_part/top/down -> bin_scatter -> gf
// ---------------------------------------------------------------------------

#define NBLK 256     // edge-blocks for binning
#define NBUC 1024    // coarse buckets = dst >> 6
#define NPB  64      // nodes per bucket
#define GCAP 2048    // max edges per bucket (avg 1024, ~32 sigma headroom)
#define MTOT (NBUC * NBLK)      // 262144
#define NPART 256               // MTOT / 1024

__device__ __forceinline__ void load_feat(const float* __restrict__ feat, size_t base,
                                          float* __restrict__ f) {
    const float4* fp = (const float4*)(feat + base);
#pragma unroll
    for (int i = 0; i < 16; ++i) {
        float4 v = fp[i];
        f[4 * i + 0] = v.x; f[4 * i + 1] = v.y;
        f[4 * i + 2] = v.z; f[4 * i + 3] = v.w;
    }
}

__device__ __forceinline__ uint32_t bf16_rne(float x) {
    uint32_t u = __float_as_uint(x);
    return (u + 0x7fffu + ((u >> 16) & 1u)) >> 16;
}

// ---- fused: blocks [0,nTf) transform nodes; blocks [nTf, nTf+NBLK) histogram.
__global__ void __launch_bounds__(512)
k_tf_hist(const float* __restrict__ feat, const float* __restrict__ norm,
          const float* __restrict__ Wn, const float* __restrict__ bn,
          const float* __restrict__ Wnh, const float* __restrict__ bnh,
          uint32_t* __restrict__ h_pk,
          const int* __restrict__ dst, int* __restrict__ blk_cnt,
          int N, int E, int nTf)
{
    __shared__ int cnt[NBUC];
    int t = threadIdx.x;

    if ((int)blockIdx.x >= nTf) {
        // ---------------- histogram path ----------------
        int hb = blockIdx.x - nTf;
        for (int i = t; i < NBUC; i += 512) cnt[i] = 0;
        __syncthreads();
        int epb = (E + NBLK - 1) / NBLK;
        int eb = hb * epb;
        for (int i0 = t * 8; i0 < epb; i0 += 512 * 8) {
            int e = eb + i0;
            if (e + 8 <= E) {
                int4 d0 = *(const int4*)(dst + e);
                int4 d1 = *(const int4*)(dst + e + 4);
                atomicAdd(&cnt[((unsigned)d0.x) >> 6], 1);
                atomicAdd(&cnt[((unsigned)d0.y) >> 6], 1);
                atomicAdd(&cnt[((unsigned)d0.z) >> 6], 1);
                atomicAdd(&cnt[((unsigned)d0.w) >> 6], 1);
                atomicAdd(&cnt[((unsigned)d1.x) >> 6], 1);
                atomicAdd(&cnt[((unsigned)d1.y) >> 6], 1);
                atomicAdd(&cnt[((unsigned)d1.z) >> 6], 1);
                atomicAdd(&cnt[((unsigned)d1.w) >> 6], 1);
            } else {
                for (int j = 0; j < 8; ++j) {
                    int ee = e + j;
                    if (ee < E) atomicAdd(&cnt[((unsigned)dst[ee]) >> 6], 1);
                }
            }
        }
        __syncthreads();
        for (int i = t; i < NBUC; i += 512)
            blk_cnt[i * NBLK + hb] = cnt[i];
        return;
    }

    // ---------------- transform path ----------------
    int nsub = t & 63;
    int q = __builtin_amdgcn_readfirstlane(t >> 6);   // octant, wave-uniform
    int n = blockIdx.x * 64 + nsub;
    if (n >= N) return;

    size_t base = (size_t)n << 6;
    float f[64];
    load_feat(feat, base, f);
    float nr = norm[n];

    uint32_t pk[8];
#pragma unroll
    for (int jj = 0; jj < 8; ++jj) {
        int j = q * 8 + jj;                            // wave-uniform row
        const float4* rL = (const float4*)(Wn  + ((size_t)j << 6));
        const float4* rH = (const float4*)(Wnh + ((size_t)j << 6));
        float sL = 0.f, sH = 0.f;
#pragma unroll
        for (int k4 = 0; k4 < 16; ++k4) {
            float4 wL = rL[k4];
            float4 wH = rH[k4];
            sL = fmaf(f[4*k4+0], wL.x, sL); sL = fmaf(f[4*k4+1], wL.y, sL);
            sL = fmaf(f[4*k4+2], wL.z, sL); sL = fmaf(f[4*k4+3], wL.w, sL);
            sH = fmaf(f[4*k4+0], wH.x, sH); sH = fmaf(f[4*k4+1], wH.y, sH);
            sH = fmaf(f[4*k4+2], wH.z, sH); sH = fmaf(f[4*k4+3], wH.w, sH);
        }
        float oL = fmaxf(sL + bn[j],  0.f) * nr;
        float oH = fmaxf(sH + bnh[j], 0.f) * nr;
        pk[jj] = bf16_rne(oL) | (bf16_rne(oH) << 16);
    }
    uint4* pp = (uint4*)(h_pk + base + q * 8);
    pp[0] = make_uint4(pk[0], pk[1], pk[2], pk[3]);
    pp[1] = make_uint4(pk[4], pk[5], pk[6], pk[7]);
}

// ---- hierarchical exclusive scan of blk_cnt[0..MTOT) -> blk_off[0..MTOT].
__global__ void __launch_bounds__(256)
k_scan_part(const int* __restrict__ cnt_in, int* __restrict__ part)
{
    __shared__ int red[256];
    int t = threadIdx.x;
    const int4* A4 = (const int4*)cnt_in;
    int4 v = A4[blockIdx.x * 256 + t];
    int s = v.x + v.y + v.z + v.w;
    red[t] = s;
    __syncthreads();
    for (int off = 128; off > 0; off >>= 1) {
        if (t < off) red[t] += red[t + off];
        __syncthreads();
    }
    if (t == 0) part[blockIdx.x] = red[0];
}

__global__ void __launch_bounds__(256)
k_scan_top(const int* __restrict__ part, int* __restrict__ top)
{
    __shared__ int s[NPART];
    int t = threadIdx.x;
    int mine = part[t];
    s[t] = mine;
    __syncthreads();
    for (int off = 1; off < NPART; off <<= 1) {
        int v = s[t];
        int a = (t >= off) ? s[t - off] : 0;
        __syncthreads();
        s[t] = v + a;
        __syncthreads();
    }
    top[t] = s[t] - mine;           // exclusive
}

__global__ void __launch_bounds__(256)
k_scan_down(const int* __restrict__ cnt_in, const int* __restrict__ top,
            int* __restrict__ off_out)
{
    __shared__ int s[256];
    int t = threadIdx.x;
    const int4* A4 = (const int4*)cnt_in;
    int4 v = A4[blockIdx.x * 256 + t];
    int sum = v.x + v.y + v.z + v.w;
    s[t] = sum;
    __syncthreads();
    for (int off = 1; off < 256; off <<= 1) {
        int vv = s[t];
        int a = (t >= off) ? s[t - off] : 0;
        __syncthreads();
        s[t] = vv + a;
        __syncthreads();
    }
    int run = top[blockIdx.x] + s[t] - sum;
    int4 o;
    o.x = run; run += v.x;
    o.y = run; run += v.y;
    o.z = run; run += v.z;
    o.w = run; run += v.w;
    ((int4*)off_out)[blockIdx.x * 256 + t] = o;
    if (blockIdx.x == (NPART - 1) && t == 255) off_out[MTOT] = run;
}

// ---- scatter edges into coarse buckets; rank via LDS atomics, contiguous runs.
// entry = (dst&63)<<16 | src
__global__ void __launch_bounds__(512)
k_bin_scatter(const int* __restrict__ src, const int* __restrict__ dst,
              const int* __restrict__ blk_off, uint32_t* __restrict__ ebuf, int E)
{
    __shared__ int base_[NBUC];
    __shared__ int cnt[NBUC];
    int t = threadIdx.x;
    for (int i = t; i < NBUC; i += 512) {
        base_[i] = blk_off[i * NBLK + blockIdx.x];
        cnt[i] = 0;
    }
    __syncthreads();
    int epb = (E + NBLK - 1) / NBLK;
    int eb = blockIdx.x * epb;
    for (int i0 = t * 8; i0 < epb; i0 += 512 * 8) {
        int e = eb + i0;
        if (e + 8 <= E) {
            int4 d0 = *(const int4*)(dst + e);
            int4 d1 = *(const int4*)(dst + e + 4);
            int4 s0 = *(const int4*)(src + e);
            int4 s1 = *(const int4*)(src + e + 4);
            int da[8] = { d0.x, d0.y, d0.z, d0.w, d1.x, d1.y, d1.z, d1.w };
            int sa[8] = { s0.x, s0.y, s0.z, s0.w, s1.x, s1.y, s1.z, s1.w };
#pragma unroll
            for (int j = 0; j < 8; ++j) {
                int b = ((unsigned)da[j]) >> 6;
                int r = atomicAdd(&cnt[b], 1);
                ebuf[base_[b] + r] = ((uint32_t)(da[j] & 63) << 16) | (uint32_t)sa[j];
            }
        } else {
            for (int j = 0; j < 8; ++j) {
                int ee = e + j;
                if (ee < E) {
                    int d = dst[ee];
                    int b = ((unsigned)d) >> 6;
                    int r = atomicAdd(&cnt[b], 1);
                    ebuf[base_[b] + r] = ((uint32_t)(d & 63) << 16) | (uint32_t)src[ee];
                }
            }
        }
    }
}

// ---- fused gather + att + out. Block = bucket = 64 dst nodes, 512 threads.
// LDS mean tiles bf16x2-packed -> 27.6 KB total -> 4 blocks/CU.
__global__ void __launch_bounds__(512)
k_gf(const uint32_t* __restrict__ h_pk, const int* __restrict__ blk_off,
     const uint32_t* __restrict__ ebuf,
     const float* __restrict__ feat,
     const float* __restrict__ Ws, const float* __restrict__ bs,
     const float* __restrict__ Wsh, const float* __restrict__ bsh,
     const float* __restrict__ Wid, const float* __restrict__ bid,
     const float* __restrict__ wl, const float* __restrict__ wh,
     const float* __restrict__ wm, const float* __restrict__ Watt,
     float* __restrict__ out, int N)
{
    __shared__ unsigned short sorted[GCAP];
    __shared__ int s_cnt[NPB];
    __shared__ int s_off[NPB];
    __shared__ uint32_t s_m[NPB][65];       // bf16x2-packed means, padded
    __shared__ float red[3][8][64];

    int b = blockIdx.x;
    int t = threadIdx.x;
    int es = blk_off[b * NBLK];
    int ee = blk_off[(b + 1) * NBLK];
    int ne = ee - es;
    if (ne > GCAP) ne = GCAP;                 // never in practice
    if (t < NPB) s_cnt[t] = 0;
    __syncthreads();

    // phase 1: read bucket edges, rank per node, counting-sort into LDS
    int ed[4], er[4], esrc[4];
#pragma unroll
    for (int i = 0; i < 4; ++i) {
        int idx = i * 512 + t;
        ed[i] = -1;
        if (idx < ne) {
            uint32_t v = ebuf[es + idx];
            ed[i] = (int)(v >> 16);
            esrc[i] = (int)(v & 0xffffu);
            er[i] = atomicAdd(&s_cnt[ed[i]], 1);
        }
    }
    __syncthreads();
    if (t < 64) {                              // wave-0 exclusive scan of 64 counts
        int c = s_cnt[t];
        int sc = c;
        for (int o = 1; o < 64; o <<= 1) {
            int u = __shfl_up(sc, o, 64);
            if (t >= o) sc += u;
        }
        s_off[t] = sc - c;
    }
    __syncthreads();
#pragma unroll
    for (int i = 0; i < 4; ++i)
        if (ed[i] >= 0) sorted[s_off[ed[i]] + er[i]] = (unsigned short)esrc[i];
    __syncthreads();

    // phase 2: wave-per-node gather; lane = channel; 8-deep MLP
    int w = t >> 6, lane = t & 63;
    for (int dd = 0; dd < 8; ++dd) {
        int d = w * 8 + dd;
        int cd = s_cnt[d];
        int od = s_off[d];
        float accL = 0.f, accH = 0.f;
        int i = 0;
        for (; i + 8 <= cd; i += 8) {
            int s0 = sorted[od + i + 0];
            int s1 = sorted[od + i + 1];
            int s2 = sorted[od + i + 2];
            int s3 = sorted[od + i + 3];
            int s4 = sorted[od + i + 4];
            int s5 = sorted[od + i + 5];
            int s6 = sorted[od + i + 6];
            int s7 = sorted[od + i + 7];
            uint32_t v0 = h_pk[((size_t)s0 << 6) + lane];
            uint32_t v1 = h_pk[((size_t)s1 << 6) + lane];
            uint32_t v2 = h_pk[((size_t)s2 << 6) + lane];
            uint32_t v3 = h_pk[((size_t)s3 << 6) + lane];
            uint32_t v4 = h_pk[((size_t)s4 << 6) + lane];
            uint32_t v5 = h_pk[((size_t)s5 << 6) + lane];
            uint32_t v6 = h_pk[((size_t)s6 << 6) + lane];
            uint32_t v7 = h_pk[((size_t)s7 << 6) + lane];
            accL += (__uint_as_float(v0 << 16) + __uint_as_float(v1 << 16))
                  + (__uint_as_float(v2 << 16) + __uint_as_float(v3 << 16))
                  + (__uint_as_float(v4 << 16) + __uint_as_float(v5 << 16))
                  + (__uint_as_float(v6 << 16) + __uint_as_float(v7 << 16));
            accH += (__uint_as_float(v0 & 0xffff0000u) + __uint_as_float(v1 & 0xffff0000u))
                  + (__uint_as_float(v2 & 0xffff0000u) + __uint_as_float(v3 & 0xffff0000u))
                  + (__uint_as_float(v4 & 0xffff0000u) + __uint_as_float(v5 & 0xffff0000u))
                  + (__uint_as_float(v6 & 0xffff0000u) + __uint_as_float(v7 & 0xffff0000u));
        }
        for (; i + 4 <= cd; i += 4) {
            int s0 = sorted[od + i + 0];
            int s1 = sorted[od + i + 1];
            int s2 = sorted[od + i + 2];
            int s3 = sorted[od + i + 3];
            uint32_t v0 = h_pk[((size_t)s0 << 6) + lane];
            uint32_t v1 = h_pk[((size_t)s1 << 6) + lane];
            uint32_t v2 = h_pk[((size_t)s2 << 6) + lane];
            uint32_t v3 = h_pk[((size_t)s3 << 6) + lane];
            accL += (__uint_as_float(v0 << 16) + __uint_as_float(v1 << 16))
                  + (__uint_as_float(v2 << 16) + __uint_as_float(v3 << 16));
            accH += (__uint_as_float(v0 & 0xffff0000u) + __uint_as_float(v1 & 0xffff0000u))
                  + (__uint_as_float(v2 & 0xffff0000u) + __uint_as_float(v3 & 0xffff0000u));
        }
        for (; i < cd; ++i) {
            int s0 = sorted[od + i];
            uint32_t v0 = h_pk[((size_t)s0 << 6) + lane];
            accL += __uint_as_float(v0 << 16);
            accH += __uint_as_float(v0 & 0xffff0000u);
        }
        float inv = 1.f / fmaxf((float)cd, 1.f);
        s_m[d][lane] = bf16_rne(accL * inv) | (bf16_rne(accH * inv) << 16);
    }
    __syncthreads();

    // phase 3: octant GEMVs + attention + combine + store
    int nsub = t & 63;
    int q = __builtin_amdgcn_readfirstlane(t >> 6);
    int n = b * 64 + nsub;
    size_t base = (size_t)n << 6;

    float f[64];
    load_feat(feat, base, f);

    float aL[8], aH[8], aI[8];
    float dLp = 0.f, dHp = 0.f, dIp = 0.f;
#pragma unroll
    for (int jj = 0; jj < 8; ++jj) {
        int j = q * 8 + jj;                            // wave-uniform row
        const float4* rL = (const float4*)(Ws  + ((size_t)j << 6));
        const float4* rH = (const float4*)(Wsh + ((size_t)j << 6));
        const float4* rI = (const float4*)(Wid + ((size_t)j << 6));
        float sL = 0.f, sH = 0.f, sI = 0.f;
#pragma unroll
        for (int k4 = 0; k4 < 16; ++k4) {
            float4 wL = rL[k4];
            float4 wH = rH[k4];
            float4 wI = rI[k4];
            sL = fmaf(f[4*k4+0], wL.x, sL); sL = fmaf(f[4*k4+1], wL.y, sL);
            sL = fmaf(f[4*k4+2], wL.z, sL); sL = fmaf(f[4*k4+3], wL.w, sL);
            sH = fmaf(f[4*k4+0], wH.x, sH); sH = fmaf(f[4*k4+1], wH.y, sH);
            sH = fmaf(f[4*k4+2], wH.z, sH); sH = fmaf(f[4*k4+3], wH.w, sH);
            sI = fmaf(f[4*k4+0], wI.x, sI); sI = fmaf(f[4*k4+1], wI.y, sI);
            sI = fmaf(f[4*k4+2], wI.z, sI); sI = fmaf(f[4*k4+3], wI.w, sI);
        }
        uint32_t mv = s_m[nsub][j];
        float lowj  = fmaxf(sL + bs[j],  0.f) + __uint_as_float(mv << 16);
        float highj = fmaxf(sH + bsh[j], 0.f) - __uint_as_float(mv & 0xffff0000u);
        float idj   = fmaxf(sI + bid[j], 0.f);
        aL[jj] = lowj; aH[jj] = highj; aI[jj] = idj;
        dLp = fmaf(lowj,  wl[j], dLp);
        dHp = fmaf(highj, wh[j], dHp);
        dIp = fmaf(idj,   wm[j], dIp);
    }

    red[0][q][nsub] = dLp;
    red[1][q][nsub] = dHp;
    red[2][q][nsub] = dIp;
    __syncthreads();
    float dL = 0.f, dH = 0.f, dI = 0.f;
#pragma unroll
    for (int p = 0; p < 8; ++p) {
        dL += red[0][p][nsub];
        dH += red[1][p][nsub];
        dI += red[2][p][nsub];
    }

    float s0 = 1.f / (1.f + expf(-dL));
    float s1 = 1.f / (1.f + expf(-dH));
    float s2 = 1.f / (1.f + expf(-dI));
    const float third = (1.f / 3.f);
    float z0 = (Watt[0] * s0 + Watt[1] * s1 + Watt[2] * s2) * third;
    float z1 = (Watt[3] * s0 + Watt[4] * s1 + Watt[5] * s2) * third;
    float z2 = (Watt[6] * s0 + Watt[7] * s1 + Watt[8] * s2) * third;
    float m = fmaxf(z0, fmaxf(z1, z2));
    float e0 = expf(z0 - m), e1 = expf(z1 - m), e2 = expf(z2 - m);
    float r = 3.f / (e0 + e1 + e2);
    float a0 = e0 * r, a1 = e1 * r, a2 = e2 * r;

    float o[8];
#pragma unroll
    for (int jj = 0; jj < 8; ++jj)
        o[jj] = a0 * aL[jj] + a1 * aH[jj] + a2 * aI[jj];
    float* po = out + base + q * 8;
    *(float4*)(po + 0) = make_float4(o[0], o[1], o[2], o[3]);
    *(float4*)(po + 4) = make_float4(o[4], o[5], o[6], o[7]);
}

extern "C" void kernel_launch(void* const* d_in, const int* in_sizes, int n_in,
                              void* d_out, int out_size, void* d_ws, size_t ws_size,
                              hipStream_t stream) {
    const float* feat         = (const float*)d_in[0];
    const float* norm         = (const float*)d_in[1];
    const int*   src          = (const int*)d_in[2];
    const int*   dst          = (const int*)d_in[3];
    const float* W_self       = (const float*)d_in[4];
    const float* b_self       = (const float*)d_in[5];
    const float* W_self_high  = (const float*)d_in[6];
    const float* b_self_high  = (const float*)d_in[7];
    const float* W_neigh      = (const float*)d_in[8];
    const float* b_neigh      = (const float*)d_in[9];
    const float* W_neigh_high = (const float*)d_in[10];
    const float* b_neigh_high = (const float*)d_in[11];
    const float* W_id         = (const float*)d_in[12];
    const float* b_id         = (const float*)d_in[13];
    const float* w_att_low    = (const float*)d_in[14];
    const float* w_att_high   = (const float*)d_in[15];
    const float* w_att_mlp    = (const float*)d_in[16];
    const float* W_att        = (const float*)d_in[17];

    int N = in_sizes[0] / 64;
    int E = in_sizes[2];
    float* out = (float*)d_out;

    size_t N64 = (size_t)N * 64;

    uint32_t* h_pk    = (uint32_t*)d_ws;                  // N*64 u32 (16 MB)
    int*      blk_cnt = (int*)(h_pk + N64);               // MTOT int
    int*      blk_off = blk_cnt + MTOT;                   // MTOT+1 int
    int*      part    = blk_off + MTOT + 16;              // NPART int
    int*      top     = part + NPART + 16;                // NPART int
    uint32_t* ebuf    = (uint32_t*)(top + NPART + 16);    // E u32 (4 MB)

    int nTf = (N + 63) / 64;

    k_tf_hist<<<dim3(nTf + NBLK), dim3(512), 0, stream>>>(
        feat, norm, W_neigh, b_neigh, W_neigh_high, b_neigh_high, h_pk,
        dst, blk_cnt, N, E, nTf);
    k_scan_part<<<dim3(NPART), dim3(256), 0, stream>>>(blk_cnt, part);
    k_scan_top<<<dim3(1), dim3(NPART), 0, stream>>>(part, top);
    k_scan_down<<<dim3(NPART), dim3(256), 0, stream>>>(blk_cnt, top, blk_off);
    k_bin_scatter<<<dim3(NBLK), dim3(512), 0, stream>>>(src, dst, blk_off, ebuf, E);
    k_gf<<<dim3(NBUC), dim3(512), 0, stream>>>(h_pk, blk_off, ebuf, feat,
                                               W_self, b_self,
                                               W_self_high, b_self_high,
                                               W_id, b_id, w_att_low, w_att_high,
                                               w_att_mlp, W_att, out, N);
}